// Round 1
// 138.362 us; speedup vs baseline: 1.0410x; 1.0410x over previous
//
#include <hip/hip_runtime.h>
#include <math.h>

// Shapes: N=8, Cout=Cin=128, ks=5.
// Output [v(128), o(8), u(128), i(8), 5, 5] fp32, 26,214,400 elems.
// out[v,o,u,i,p,q] = mask[p,q] * bilinear( (1-frac_i)*W[g0_i,u,v,:,:] + frac_i*W[g1_i,u,v,:,:],
//                                          rot_o(grid_Rn)[p,q] )
//
// v2 structure: block = (o, 8u x 8v tile), ALL 8 i, ALL 8 g staged raw.
//   phase 1: global_load_lds dwordx4 linear copy of the 8 g-slices (51.2 KB,
//            no blend, no VGPR round-trip). Read traffic 4x lower than v1
//            (each tile staged once per o instead of twice per (o,i)).
//   phase 2: lane = (i = t>>5, k = t&31, k<25 active). Blend folded into the
//            8 tap weights (om/frac premultiplied), 4 ds_read2_b32 + 8 FMA +
//            1 store per output. Wave-store = 50 consecutive dwords; all 8 i
//            of each 800B output run written by THIS block back-to-back ->
//            full-line HBM writes from a single XCD's L2 (v1 split lines
//            across blocks on the i axis).
// LDS bank check: taps rb in [0,24] -> distinct values = distinct banks within
// each 25-lane k-group; 2 i-groups/wave -> <=2-way conflict = free (m136).

#define TWO_PI_F 6.28318530717958647692f

typedef const void __attribute__((address_space(1)))* gas_cvp;
typedef void __attribute__((address_space(3)))* las_vp;

__device__ __forceinline__ void gload_lds16(const float* g, float* l) {
    __builtin_amdgcn_global_load_lds((gas_cvp)g, (las_vp)l, 16, 0, 0);
}

__global__ __launch_bounds__(256, 3) void rotconv_weight_kernel(
    const float* __restrict__ in_H,    // [8]
    const float* __restrict__ out_H,   // [8]
    const float* __restrict__ weight,  // [8,128,128,5,5]
    const float* __restrict__ grid_Rn, // [2,5,5]
    const float* __restrict__ mask,    // [25]
    float* __restrict__ out)
{
    __shared__ __align__(16) float s_tile[12800]; // [g=8][u=8][v=8][25] = 51.2 KB

    const int t  = threadIdx.x;
    const int bx = blockIdx.x;
    const int vt = bx & 15;         // v-tile (8 wide)
    const int ut = (bx >> 4) & 15;  // u-tile (8 wide)
    const int o  = bx >> 8;         // 0..7
    const int u0 = ut * 8;
    const int v0 = vt * 8;

    // ---- phase 1: async-stage all 8 g-slices of this 8u x 8v tile ----
    // chunk (g,uu) = 200 contiguous floats (v0..v0+7 x 25) both in global and
    // LDS -> linear mapping, LDS dest = wave-uniform base + lane*16.
#pragma unroll
    for (int j = 0; j < 13; ++j) {
        const int f = t + j * 256;            // float4 index, 3200 total
        if (f < 3200) {                       // j=12: t<128 -> wave-uniform
            const int c  = f / 50;            // chunk = g*8 + uu
            const int w4 = f - c * 50;        // float4 within chunk (0..49)
            const int g  = c >> 3;
            const int uu = c & 7;
            const float* gp = weight +
                (size_t)((((g * 128) + u0 + uu) * 128 + v0) * 25 + (w4 << 2));
            float* lp = s_tile + (((j * 256) + (t & 192)) << 2);
            gload_lds16(gp, lp);
        }
    }

    // ---- per-thread setup while the staging loads are in flight ----
    const float ang = -out_H[o];
    const int k  = t & 31;          // kernel tap position (k<25 active)
    const int i  = t >> 5;          // own input-rotation index 0..7
    const int kk = k < 25 ? k : 0;

    // rotation-bin blend factors for OWN i
    const float theta = in_H[i] + ang;
    float mth = fmodf(theta, TWO_PI_F);
    if (mth < 0.0f) mth += TWO_PI_F;
    const float pos  = mth * (8.0f / TWO_PI_F);
    const float pf   = floorf(pos);
    const float frac = pos - pf;
    const int g0 = ((int)pf) & 7;
    const int g1 = (g0 + 1) & 7;
    const float om = 1.0f - frac;

    // tap coefficients for OWN k (x-clamp folded so taps = adjacent pair)
    int rb0, rb1;
    float w00, w01, w10, w11;
    {
        float sthe, cthe;
        sincosf(ang, &sthe, &cthe);
        const float X = grid_Rn[kk];
        const float Y = grid_Rn[25 + kk];
        const float gx = cthe * X - sthe * Y;
        const float gy = sthe * X + cthe * Y;
        const float x = (gx + 1.0f) * 2.0f;   // * 0.5 * (W-1), W=5
        const float y = (gy + 1.0f) * 2.0f;
        const float x0f = floorf(x);
        const float y0f = floorf(y);
        const float fx = x - x0f;             // ref uses unclamped floor
        const float fy = y - y0f;
        int x0 = (int)x0f; x0 = x0 < 0 ? 0 : (x0 > 4 ? 4 : x0);
        int y0 = (int)y0f; y0 = y0 < 0 ? 0 : (y0 > 4 ? 4 : y0);
        const int y1 = y0 + 1 > 4 ? 4 : y0 + 1;
        const float mk = mask[kk];
        float wa = mk * (1.0f - fy) * (1.0f - fx);
        float wb = mk * (1.0f - fy) * fx;
        float wc = mk * fy * (1.0f - fx);
        float wd = mk * fy * fx;
        int xb = x0;
        if (x0 == 4) { xb = 3; wb += wa; wa = 0.0f; wd += wc; wc = 0.0f; }
        rb0 = y0 * 5 + xb;
        rb1 = y1 * 5 + xb;
        w00 = wa; w01 = wb; w10 = wc; w11 = wd;
    }
    // fold the g0/g1 blend into the tap weights: 8 FMA per output, no lerp
    const float w00o = w00 * om,   w01o = w01 * om,
                w10o = w10 * om,   w11o = w11 * om;
    const float w00f = w00 * frac, w01f = w01 * frac,
                w10f = w10 * frac, w11f = w11 * frac;

    __syncthreads();   // compiler drains vmcnt(0) for the global_load_lds

    // ---- phase 2: sample + blend + store ----
    if (k < 25) {
        const float* base0 = s_tile + g0 * 1600;   // g-slice = 64 rows * 25
        const float* base1 = s_tile + g1 * 1600;
        float* op = out + ((((size_t)v0 * 8 + o) * 128 + u0) * 8 + i) * 25 + kk;
#pragma unroll
        for (int vv = 0; vv < 8; ++vv) {
            const float* p0a = base0 + vv * 25 + rb0;
            const float* p0b = base0 + vv * 25 + rb1;
            const float* p1a = base1 + vv * 25 + rb0;
            const float* p1b = base1 + vv * 25 + rb1;
            float* ov = op + (size_t)vv * 204800;  // v stride = 8*128*8*25
#pragma unroll
            for (int uu = 0; uu < 8; ++uu) {
                const int d = uu * 200;            // u stride in LDS rows (8*25)
                const float a00 = p0a[d], a01 = p0a[d + 1];
                const float a10 = p0b[d], a11 = p0b[d + 1];
                const float b00 = p1a[d], b01 = p1a[d + 1];
                const float b10 = p1b[d], b11 = p1b[d + 1];
                float r = a00 * w00o;
                r = fmaf(a01, w01o, r);
                r = fmaf(a10, w10o, r);
                r = fmaf(a11, w11o, r);
                r = fmaf(b00, w00f, r);
                r = fmaf(b01, w01f, r);
                r = fmaf(b10, w10f, r);
                r = fmaf(b11, w11f, r);
                ov[d] = r;                         // wave: 50 consecutive dwords
            }
        }
    }
}

extern "C" void kernel_launch(void* const* d_in, const int* in_sizes, int n_in,
                              void* d_out, int out_size, void* d_ws, size_t ws_size,
                              hipStream_t stream) {
    const float* in_H    = (const float*)d_in[0];
    const float* out_H   = (const float*)d_in[1];
    const float* weight  = (const float*)d_in[2];
    // d_in[3] = grid_H (unused)
    const float* grid_Rn = (const float*)d_in[4];
    const float* mask    = (const float*)d_in[5];
    float* out = (float*)d_out;

    // 8 o x 16 u-tiles x 16 v-tiles = 2048 blocks
    rotconv_weight_kernel<<<dim3(2048), dim3(256), 0, stream>>>(
        in_H, out_H, weight, grid_Rn, mask, out);
}

// Round 2
// 136.117 us; speedup vs baseline: 1.0582x; 1.0165x over previous
//
#include <hip/hip_runtime.h>
#include <math.h>

// Shapes: N=8, Cout=Cin=128, ks=5.
// Output [v(128), o(8), u(128), i(8), 5, 5] fp32, 26,214,400 elems.
// out[v,o,u,i,p,q] = mask[p,q] * bilinear( (1-frac_i)*W[g0_i,u,v,:,:] + frac_i*W[g1_i,u,v,:,:],
//                                          rot_o(grid_Rn)[p,q] )
//
// v3: block = (o, 4u x 8v tile), all 8 i. LDS holds BLENDED per-i tiles
// (blend folded into staging), so phase 2 gathers only 4 floats/output.
//   phase 1: float4 global loads of g0_i/g1_i rows -> VGPR blend ->
//            ds_write_b128. [i][uu][vv][25] layout, i-stride padded to 808.
//   phase 2: lane = (i = t/25, k = t%25), t<200 active. x-clamp AND y-clamp
//            folded into tap weights so the 4 taps are {0,1,5,6} off one
//            per-lane LDS address -> 2 ds_read2_b32 per output (v2 used 4).
//            Store: addr = base(vv,uu) + t -> 64 consecutive dwords per wave
//            (256B fully coalesced; v2 wasted 14/64 lanes).

#define TWO_PI_F 6.28318530717958647692f

__global__ __launch_bounds__(256, 4) void rotconv_weight_kernel(
    const float* __restrict__ in_H,    // [8]
    const float* __restrict__ out_H,   // [8]
    const float* __restrict__ weight,  // [8,128,128,5,5]
    const float* __restrict__ grid_Rn, // [2,5,5]
    const float* __restrict__ mask,    // [25]
    float* __restrict__ out)
{
    // blended tiles: [i=8][uu=4][vv=8][25]; i-stride 800 padded to 808 floats
    // (808 % 32 = 8 -> i-groups land on shifted banks)
    __shared__ __align__(16) float s_bl[8 * 808];   // 25.9 KB

    const int t  = threadIdx.x;
    const int bx = blockIdx.x;
    const int vt = bx & 15;          // 16 v-tiles of 8
    const int ut = (bx >> 4) & 31;   // 32 u-tiles of 4
    const int o  = bx >> 9;          // 0..7
    const int u0 = ut * 4;
    const int v0 = vt * 8;

    const float ang = -out_H[o];

    // ---- phase 1: load g0/g1 rows, blend in VGPR, write blended to LDS ----
    // 1600 float4 over [i][uu][c<50]; per-(i) chunk = 4u x (8v x 25) = 800 floats,
    // contiguous 200-float (800B) sub-chunks per uu in both global and LDS.
#pragma unroll
    for (int j = 0; j < 7; ++j) {
        const int f4 = t + j * 256;
        if (f4 < 1600) {                       // j<6 always true; j=6: wave 0 only
            const int ii = f4 / 200;
            const int r4 = f4 - ii * 200;
            const int uu = r4 / 50;
            const int c  = r4 - uu * 50;
            // rotation-bin blend factors for ii (recomputed per iter; L1-hot)
            const float theta = in_H[ii] + ang;
            float m = fmodf(theta, TWO_PI_F);
            if (m < 0.0f) m += TWO_PI_F;
            const float pos = m * (8.0f / TWO_PI_F);
            const float pf  = floorf(pos);
            const float fr  = pos - pf;
            const int g0 = ((int)pf) & 7;
            const int g1 = (g0 + 1) & 7;
            const float om = 1.0f - fr;
            const size_t rowg = (size_t)(u0 + uu) * 128 + v0;   // row in [128][128]
            const float4 a0 = *reinterpret_cast<const float4*>(
                weight + ((size_t)g0 * 16384 + rowg) * 25 + (c << 2));
            const float4 a1 = *reinterpret_cast<const float4*>(
                weight + ((size_t)g1 * 16384 + rowg) * 25 + (c << 2));
            float4 bl;
            bl.x = om * a0.x + fr * a1.x;
            bl.y = om * a0.y + fr * a1.y;
            bl.z = om * a0.z + fr * a1.z;
            bl.w = om * a0.w + fr * a1.w;
            *reinterpret_cast<float4*>(s_bl + ii * 808 + (r4 << 2)) = bl;
        }
    }

    // ---- per-thread tap setup: i = t/25, k = t%25 (t<200 active) ----
    const int i = t / 25;            // 0..7 for active threads
    const int k = t - i * 25;        // 0..24 always
    int rb0;
    float w00, w01, w10, w11;
    {
        float sthe, cthe;
        sincosf(ang, &sthe, &cthe);
        const float X = grid_Rn[k];
        const float Y = grid_Rn[25 + k];
        const float gx = cthe * X - sthe * Y;
        const float gy = sthe * X + cthe * Y;
        const float x = (gx + 1.0f) * 2.0f;   // * 0.5 * (W-1), W=5
        const float y = (gy + 1.0f) * 2.0f;
        const float x0f = floorf(x);
        const float y0f = floorf(y);
        const float fx = x - x0f;             // ref uses unclamped floor
        const float fy = y - y0f;
        int x0 = (int)x0f; x0 = x0 < 0 ? 0 : (x0 > 4 ? 4 : x0);
        int y0 = (int)y0f; y0 = y0 < 0 ? 0 : (y0 > 4 ? 4 : y0);
        const float mk = mask[k];
        float wa = mk * (1.0f - fy) * (1.0f - fx);
        float wb = mk * (1.0f - fy) * fx;
        float wc = mk * fy * (1.0f - fx);
        float wd = mk * fy * fx;
        // x-clamp fold: x1==x0==4 -> taps collapse onto x=4; use pair (3,4)
        if (x0 == 4) { x0 = 3; wb += wa; wa = 0.0f; wd += wc; wc = 0.0f; }
        // y-clamp fold: y1==y0==4 -> rows collapse onto y=4; use rows (3,4)
        if (y0 == 4) { y0 = 3; wc += wa; wa = 0.0f; wd += wb; wb = 0.0f; }
        rb0 = y0 * 5 + x0;                    // <= 18; taps at {0,1,5,6}
        w00 = wa; w01 = wb; w10 = wc; w11 = wd;
    }

    __syncthreads();

    // ---- phase 2: 2 x ds_read2_b32 + 4 FMA + 1 coalesced store per output ----
    if (t < 200) {
        const float* rowb = s_bl + i * 808 + rb0;
        // out index = ((v*8+o)*128+u)*200 + (i*25+k);  i*25+k == t
        float* op = out + (size_t)((v0 * 8 + o) * 128 + u0) * 200 + t;
#pragma unroll
        for (int vv = 0; vv < 8; ++vv) {
            const float* p = rowb + vv * 25;
            float* ov = op + (size_t)vv * 204800;   // v-stride = 8*128*200
#pragma unroll
            for (int uu = 0; uu < 4; ++uu) {
                const float* q = p + uu * 200;      // u-stride in LDS floats
                const float v00 = q[0], v01 = q[1];
                const float v10 = q[5], v11 = q[6];
                ov[uu * 200] =
                    fmaf(w00, v00, fmaf(w01, v01, fmaf(w10, v10, w11 * v11)));
            }
        }
    }
}

extern "C" void kernel_launch(void* const* d_in, const int* in_sizes, int n_in,
                              void* d_out, int out_size, void* d_ws, size_t ws_size,
                              hipStream_t stream) {
    const float* in_H    = (const float*)d_in[0];
    const float* out_H   = (const float*)d_in[1];
    const float* weight  = (const float*)d_in[2];
    // d_in[3] = grid_H (unused)
    const float* grid_Rn = (const float*)d_in[4];
    const float* mask    = (const float*)d_in[5];
    float* out = (float*)d_out;

    // 8 o x 32 u-tiles x 16 v-tiles = 4096 blocks
    rotconv_weight_kernel<<<dim3(4096), dim3(256), 0, stream>>>(
        in_H, out_H, weight, grid_Rn, mask, out);
}